// Round 8
// baseline (423.245 us; speedup 1.0000x reference)
//
#include <hip/hip_runtime.h>
#include <hip/hip_cooperative_groups.h>

namespace cg = cooperative_groups;

#define B_    64
#define C_    2048
#define HW_   288
#define EPS_  0.07f
#define TINY_ 1e-8f
#define NCH_  64
#define CPC_  (C_ / NCH_)   // 32 rows per chunk
#define NJOB_ (B_ * 16)     // 1024 logical block-jobs for P1/P3

__device__ __forceinline__ float comp(const float4 v, int i) {
  return i == 0 ? v.x : i == 1 ? v.y : i == 2 ? v.z : v.w;
}

__device__ __forceinline__ void acc3(const float4 v, float a0, float a1,
                                     float* ssq, float* sd0, float* sd1) {
  ssq[0] += v.x * v.x; ssq[1] += v.y * v.y; ssq[2] += v.z * v.z; ssq[3] += v.w * v.w;
  sd0[0] += v.x * a0;  sd0[1] += v.y * a0;  sd0[2] += v.z * a0;  sd0[3] += v.w * a0;
  sd1[0] += v.x * a1;  sd1[1] += v.y * a1;  sd1[2] += v.z * a1;  sd1[3] += v.w * a1;
}

// ---------------------------------------------------------------------------
// P1 body: per-token partials for block-job bi. One C-chunk per wave.
// Deep pipeline: 8-row ping-pong groups (~8 outstanding 1KB loads/wave).
// ---------------------------------------------------------------------------
__device__ __forceinline__ void p1_body(
    const float* __restrict__ x, const float* __restrict__ anchors,
    float* __restrict__ part, int bi, int t) {
  int b  = bi >> 4;
  int cg_ = bi & 15;
  int lane = t & 63, wid = t >> 6;
  int ch = cg_ * 4 + wid;
  int c0 = ch * CPC_;
  const float* xb = x + ((size_t)b * C_ + c0) * HW_;
  const float4* a0v = (const float4*)(anchors + c0);        // c0 % 32 == 0
  const float4* a1v = (const float4*)(anchors + C_ + c0);

  float ssq[4] = {0,0,0,0}, sd0[4] = {0,0,0,0}, sd1[4] = {0,0,0,0};

  // 8-row ping-pong: bufX[p][8], bufA[p][0..1]=a0 halves, [2..3]=a1 halves
  float4 bufX[2][8], bufA[2][4];
#pragma unroll
  for (int j = 0; j < 8; ++j)
    bufX[0][j] = ((const float4*)(xb + (size_t)j * HW_))[lane];
  bufA[0][0] = a0v[0]; bufA[0][1] = a0v[1];
  bufA[0][2] = a1v[0]; bufA[0][3] = a1v[1];

#pragma unroll
  for (int g = 0; g < CPC_ / 8; ++g) {
    const int cur = g & 1, nxt = cur ^ 1;
    if (g + 1 < CPC_ / 8) {
#pragma unroll
      for (int j = 0; j < 8; ++j)
        bufX[nxt][j] = ((const float4*)(xb + (size_t)((g + 1) * 8 + j) * HW_))[lane];
      bufA[nxt][0] = a0v[2 * (g + 1)];     bufA[nxt][1] = a0v[2 * (g + 1) + 1];
      bufA[nxt][2] = a1v[2 * (g + 1)];     bufA[nxt][3] = a1v[2 * (g + 1) + 1];
    }
#pragma unroll
    for (int j = 0; j < 8; ++j)
      acc3(bufX[cur][j], comp(bufA[cur][j >> 2], j & 3),
           comp(bufA[cur][2 + (j >> 2)], j & 3), ssq, sd0, sd1);
  }

  // tail: h float4s 64..71; lane covers rows k*8+(lane>>3), q=lane&7
  int rg = lane >> 3, q = lane & 7;
  float4 tv[4];
  float ta0[4], ta1[4];
#pragma unroll
  for (int k = 0; k < CPC_ / 8; ++k) {
    int r = k * 8 + rg;
    tv[k]  = ((const float4*)(xb + (size_t)r * HW_))[64 + q];
    ta0[k] = anchors[c0 + r];
    ta1[k] = anchors[C_ + c0 + r];
  }
  float tsq[4] = {0,0,0,0}, td0[4] = {0,0,0,0}, td1[4] = {0,0,0,0};
#pragma unroll
  for (int k = 0; k < CPC_ / 8; ++k)
    acc3(tv[k], ta0[k], ta1[k], tsq, td0, td1);
#pragma unroll
  for (int off = 8; off < 64; off <<= 1) {
#pragma unroll
    for (int j = 0; j < 4; ++j) {
      tsq[j] += __shfl_xor(tsq[j], off);
      td0[j] += __shfl_xor(td0[j], off);
      td1[j] += __shfl_xor(td1[j], off);
    }
  }

  size_t PS = (size_t)B_ * NCH_ * HW_;
  float* base = part + (size_t)(b * NCH_ + ch) * HW_;
  ((float4*)base)[lane]          = make_float4(ssq[0], ssq[1], ssq[2], ssq[3]);
  ((float4*)(base + PS))[lane]   = make_float4(sd0[0], sd0[1], sd0[2], sd0[3]);
  ((float4*)(base + 2*PS))[lane] = make_float4(sd1[0], sd1[1], sd1[2], sd1[3]);
  if (lane < 8) {
    ((float4*)base)[64 + lane]          = make_float4(tsq[0], tsq[1], tsq[2], tsq[3]);
    ((float4*)(base + PS))[64 + lane]   = make_float4(td0[0], td0[1], td0[2], td0[3]);
    ((float4*)(base + 2*PS))[64 + lane] = make_float4(td1[0], td1[1], td1[2], td1[3]);
  }
}

// ---------------------------------------------------------------------------
// P3 body: masked pooling for block-job bi (same c-range as P1's job bi).
// Transaction-coalesced octant map (oct + 8j), register-resident masks.
// ---------------------------------------------------------------------------
__device__ __forceinline__ void p3_body(
    const float* __restrict__ x, const float* __restrict__ m,
    const float* __restrict__ invden, float* __restrict__ out, int bi, int t) {
  int b = bi >> 4, seg = bi & 15;
  int oct = t & 7, rl = t >> 3;

  const float4* m0 = (const float4*)(m + (b * 2 + 0) * HW_);
  const float4* m1 = (const float4*)(m + (b * 2 + 1) * HW_);
  float4 w0[9], w1[9];
#pragma unroll
  for (int j = 0; j < 9; ++j) {
    w0[j] = m0[oct + 8 * j];
    w1[j] = m1[oct + 8 * j];
  }
  float inv0 = invden[2 * b], inv1 = invden[2 * b + 1];

  int cbase = seg * 128;
#pragma unroll 1
  for (int g = 0; g < 4; ++g) {
    int c = cbase + g * 32 + rl;
    const float4* xr = (const float4*)(x + ((size_t)b * C_ + c) * HW_);
    float4 xa[9];
#pragma unroll
    for (int j = 0; j < 9; ++j) xa[j] = xr[oct + 8 * j];
    float a0 = 0.f, a1 = 0.f;
#pragma unroll
    for (int j = 0; j < 9; ++j) {
      a0 += xa[j].x * w0[j].x + xa[j].y * w0[j].y + xa[j].z * w0[j].z + xa[j].w * w0[j].w;
      a1 += xa[j].x * w1[j].x + xa[j].y * w1[j].y + xa[j].z * w1[j].z + xa[j].w * w1[j].w;
    }
#pragma unroll
    for (int off = 4; off >= 1; off >>= 1) {
      a0 += __shfl_xor(a0, off);
      a1 += __shfl_xor(a1, off);
    }
    if (oct == 0) {
      out[(size_t)b * C_ + c] = a0 * inv0;
      out[(size_t)B_ * C_ + (size_t)b * C_ + c] = a1 * inv1;
    }
  }
}

// Block-wide 2-value sum reduction, NW waves, broadcast to all threads.
template <int NW>
__device__ __forceinline__ void block_reduce2(
    float& p0, float& p1, volatile float* r0, volatile float* r1, int t) {
  int lane = t & 63, wid = t >> 6;
#pragma unroll
  for (int off = 32; off >= 1; off >>= 1) {
    p0 += __shfl_down(p0, off);
    p1 += __shfl_down(p1, off);
  }
  __syncthreads();
  if (lane == 0) { r0[wid] = p0; r1[wid] = p1; }
  __syncthreads();
  float s0 = 0.f, s1 = 0.f;
#pragma unroll
  for (int w = 0; w < NW; ++w) { s0 += r0[w]; s1 += r1[w]; }
  p0 = s0; p1 = s1;
}

// ---------------------------------------------------------------------------
// Fused cooperative kernel. Grid-stride phases; works for any gridDim <= NJOB_.
// ---------------------------------------------------------------------------
__global__ __launch_bounds__(256, 4) void mega(
    const float* __restrict__ x, const float* __restrict__ anchors,
    float* __restrict__ part, float* __restrict__ invden,
    float* __restrict__ out) {
  cg::grid_group grid = cg::this_grid();
  __shared__ float s_r0[4], s_r1[4];
  int t = threadIdx.x;
  float* out_m = out + 2 * B_ * C_;

  // P1
  for (int bi = blockIdx.x; bi < NJOB_; bi += gridDim.x)
    p1_body(x, anchors, part, bi, t);

  grid.sync();

  // P2a: collapse NCH chunk-partials -> reuse part's plane-0 head? No:
  // write red into invden+128 region (red laid after invden in ws).
  // red[idx], idx < 3*B*HW.
  {
    float* red = invden + 128 + 0;  // caller reserves: invden[128] | red | part
    for (int idx = blockIdx.x * 256 + t; idx < 3 * B_ * HW_;
         idx += gridDim.x * 256) {
      int plane = idx / (B_ * HW_);
      int rem = idx - plane * (B_ * HW_);
      int b = rem / HW_;
      int h = rem - b * HW_;
      const float* p = part + (size_t)plane * B_ * NCH_ * HW_
                            + (size_t)b * NCH_ * HW_ + h;
      float s = 0.f;
#pragma unroll 8
      for (int ch = 0; ch < NCH_; ++ch) s += p[(size_t)ch * HW_];
      red[idx] = s;
    }
  }

  grid.sync();

  // P2b: Sinkhorn, 64 jobs, 256 threads each (t handles h=t and h=256+t).
  for (int b = blockIdx.x; b < B_; b += gridDim.x) {
    const float* red = invden + 128;
    float a0 = 0.f, a1 = 0.f;
    for (int c = t; c < C_; c += 256) {
      float q0 = anchors[c], q1 = anchors[C_ + c];
      a0 += q0 * q0; a1 += q1 * q1;
    }
    block_reduce2<4>(a0, a1, s_r0, s_r1, t);
    float ian0 = 1.0f / fmaxf(sqrtf(a0), 1e-12f);
    float ian1 = 1.0f / fmaxf(sqrtf(a1), 1e-12f);

    bool hb = t < (HW_ - 256);
    float Ka0, Ka1, Kb0 = 0.f, Kb1 = 0.f;
    {
      float ssq = red[b * HW_ + t];
      float d0  = red[B_ * HW_ + b * HW_ + t];
      float d1  = red[2 * B_ * HW_ + b * HW_ + t];
      float ixn = 1.0f / fmaxf(sqrtf(ssq), 1e-12f);
      Ka0 = expf((d0 * ixn * ian0 - 1.0f) / EPS_) + TINY_;
      Ka1 = expf((d1 * ixn * ian1 - 1.0f) / EPS_) + TINY_;
    }
    if (hb) {
      int h = 256 + t;
      float ssq = red[b * HW_ + h];
      float d0  = red[B_ * HW_ + b * HW_ + h];
      float d1  = red[2 * B_ * HW_ + b * HW_ + h];
      float ixn = 1.0f / fmaxf(sqrtf(ssq), 1e-12f);
      Kb0 = expf((d0 * ixn * ian0 - 1.0f) / EPS_) + TINY_;
      Kb1 = expf((d1 * ixn * ian1 - 1.0f) / EPS_) + TINY_;
    }

    float v0 = 1.f, v1 = 1.f, ua = 0.f, ub = 0.f;
    const float ia = 1.0f / (float)HW_;
    for (int it = 0; it < 7; ++it) {
      ua = ia / (Ka0 * v0 + Ka1 * v1 + TINY_);
      ub = ia / (Kb0 * v0 + Kb1 * v1 + TINY_);
      float p0 = Ka0 * ua + (hb ? Kb0 * ub : 0.f);
      float p1 = Ka1 * ua + (hb ? Kb1 * ub : 0.f);
      block_reduce2<4>(p0, p1, s_r0, s_r1, t);
      v0 = 0.5f / (p0 + TINY_);
      v1 = 0.5f / (p1 + TINY_);
    }

    float ma0 = Ka0 * ua * v0 * (float)HW_;
    float ma1 = Ka1 * ua * v1 * (float)HW_;
    float mb0 = hb ? Kb0 * ub * v0 * (float)HW_ : 0.f;
    float mb1 = hb ? Kb1 * ub * v1 * (float)HW_ : 0.f;
    float q0 = ma0 + mb0, q1 = ma1 + mb1;
    block_reduce2<4>(q0, q1, s_r0, s_r1, t);

    out_m[(b * 2 + 0) * HW_ + t] = ma0;
    out_m[(b * 2 + 1) * HW_ + t] = ma1;
    if (hb) {
      out_m[(b * 2 + 0) * HW_ + 256 + t] = mb0;
      out_m[(b * 2 + 1) * HW_ + 256 + t] = mb1;
    }
    if (t == 0) {
      invden[b * 2 + 0] = 1.0f / (q0 + 1e-6f);
      invden[b * 2 + 1] = 1.0f / (q1 + 1e-6f);
    }
  }

  grid.sync();

  // P3
  for (int bi = blockIdx.x; bi < NJOB_; bi += gridDim.x)
    p3_body(x, out_m, invden, out, bi, t);
}

// ---------------------- fallback path (R7 structure) -----------------------
__global__ __launch_bounds__(256) void k1_partials(
    const float* __restrict__ x, const float* __restrict__ anchors,
    float* __restrict__ part) {
  p1_body(x, anchors, part, blockIdx.x, threadIdx.x);
}

__global__ __launch_bounds__(320) void k2_sinkhorn(
    const float* __restrict__ part, const float* __restrict__ anchors,
    float* __restrict__ out_m, float* __restrict__ invden) {
  int b = blockIdx.x, t = threadIdx.x;
  __shared__ float red0[8], red1[8];

  float a0 = 0.f, a1 = 0.f;
  for (int c = t; c < C_; c += 320) {
    float q0 = anchors[c], q1 = anchors[C_ + c];
    a0 += q0 * q0; a1 += q1 * q1;
  }
  block_reduce2<5>(a0, a1, red0, red1, t);
  float ian0 = 1.0f / fmaxf(sqrtf(a0), 1e-12f);
  float ian1 = 1.0f / fmaxf(sqrtf(a1), 1e-12f);

  float K0 = 0.f, K1 = 0.f;
  if (t < HW_) {
    size_t PS = (size_t)B_ * NCH_ * HW_;
    const float* p = part + (size_t)b * NCH_ * HW_ + t;
    float ssq = 0.f, d0 = 0.f, d1 = 0.f;
#pragma unroll 8
    for (int ch = 0; ch < NCH_; ++ch) {
      size_t o = (size_t)ch * HW_;
      ssq += p[o];
      d0  += p[PS + o];
      d1  += p[2 * PS + o];
    }
    float ixn = 1.0f / fmaxf(sqrtf(ssq), 1e-12f);
    K0 = expf((d0 * ixn * ian0 - 1.0f) / EPS_) + TINY_;
    K1 = expf((d1 * ixn * ian1 - 1.0f) / EPS_) + TINY_;
  }

  float v0 = 1.f, v1 = 1.f, u = 0.f;
  for (int it = 0; it < 7; ++it) {
    if (t < HW_) u = (1.0f / (float)HW_) / (K0 * v0 + K1 * v1 + TINY_);
    float p0 = K0 * u, p1 = K1 * u;
    block_reduce2<5>(p0, p1, red0, red1, t);
    v0 = 0.5f / (p0 + TINY_);
    v1 = 0.5f / (p1 + TINY_);
  }

  float m0 = 0.f, m1 = 0.f;
  if (t < HW_) {
    m0 = K0 * u * v0 * (float)HW_;
    m1 = K1 * u * v1 * (float)HW_;
  }
  float q0 = m0, q1 = m1;
  block_reduce2<5>(q0, q1, red0, red1, t);
  if (t < HW_) {
    out_m[(b * 2 + 0) * HW_ + t] = m0;
    out_m[(b * 2 + 1) * HW_ + t] = m1;
  }
  if (t == 0) {
    invden[b * 2 + 0] = 1.0f / (q0 + 1e-6f);
    invden[b * 2 + 1] = 1.0f / (q1 + 1e-6f);
  }
}

__global__ __launch_bounds__(256) void k3_pool(
    const float* __restrict__ x, const float* __restrict__ m,
    const float* __restrict__ invden, float* __restrict__ out) {
  p3_body(x, m, invden, out, blockIdx.x, threadIdx.x);
}

extern "C" void kernel_launch(void* const* d_in, const int* in_sizes, int n_in,
                              void* d_out, int out_size, void* d_ws, size_t ws_size,
                              hipStream_t stream) {
  const float* x       = (const float*)d_in[0];
  const float* anchors = (const float*)d_in[1];
  float* out = (float*)d_out;

  // ws layout: invden[128] | red[3*B*HW] | part[3*B*NCH*288]
  float* invden = (float*)d_ws;
  float* part = invden + 128 + 3 * B_ * HW_;
  float* out_m = out + 2 * B_ * C_;

  // Try cooperative fused launch; fall back to 3-kernel path on any failure.
  int blocksPerCU = 0;
  hipError_t e = hipOccupancyMaxActiveBlocksPerMultiprocessor(
      &blocksPerCU, (const void*)mega, 256, 0);
  bool coop_ok = (e == hipSuccess && blocksPerCU > 0);
  if (coop_ok) {
    int maxBlocks = blocksPerCU * 256;          // 256 CUs on MI355X
    int gridSize = maxBlocks < NJOB_ ? maxBlocks : NJOB_;
    void* args[] = {(void*)&x, (void*)&anchors, (void*)&part,
                    (void*)&invden, (void*)&out};
    e = hipLaunchCooperativeKernel((const void*)mega, dim3(gridSize), dim3(256),
                                   args, 0, stream);
    coop_ok = (e == hipSuccess);
  }
  if (!coop_ok) {
    k1_partials<<<NJOB_, 256, 0, stream>>>(x, anchors, part);
    k2_sinkhorn<<<B_, 320, 0, stream>>>(part, anchors, out_m, invden);
    k3_pool<<<NJOB_, 256, 0, stream>>>(x, out_m, invden, out);
  }
}